// Round 1
// baseline (2263.120 us; speedup 1.0000x reference)
//
#include <hip/hip_runtime.h>
#include <math.h>

// Problem constants (fixed by the reference).
namespace {
constexpr int HWF   = 256;     // feature dim (H*W)
constexpr int MEMD  = 1024;    // memory slots
constexpr int NROWS = 65536;   // N_TOKENS * BATCH
constexpr int TM    = 64;      // token rows per block
constexpr int TJ    = 64;      // memory slots per tile
constexpr int NT    = MEMD / TJ;  // 16 tiles
constexpr float C1v  = 0.01f;
constexpr float C2v  = 0.03f;
constexpr float EPSv = 1e-8f;

// LDS strides (floats). Chosen for bank-conflict-freedom + 16B alignment.
constexpr int QT_S = 68;   // Qt[k][r]: 256 x 68  (transposed q, b128 reads on r)
constexpr int K_S  = 257;  // K[j][k]:  64 x 257  (+1 pad: 2-way max on strided reads)
constexpr int V_S  = 260;  // V[j][c]:  64 x 260  (mult-of-4 pad: aligned float4 reads)
constexpr int P_S  = 65;   // P[r][j]:  64 x 65
}

// ---------------------------------------------------------------------------
// Kernel 1: k = m@Wk^T (centered, + mean/var stats), v = m@Wv^T.
// One block per memory slot j; thread t owns output feature t.
// ---------------------------------------------------------------------------
__global__ __launch_bounds__(256) void prep_kv(
    const float* __restrict__ mem, const float* __restrict__ Wk,
    const float* __restrict__ Wv, float* __restrict__ kc,
    float* __restrict__ vout, float* __restrict__ km, float* __restrict__ kv)
{
    __shared__ __align__(16) float mrow[HWF];
    __shared__ float red[256];
    const int j = blockIdx.x;
    const int t = threadIdx.x;

    mrow[t] = mem[(size_t)j * HWF + t];
    __syncthreads();

    const float4* wk4 = reinterpret_cast<const float4*>(Wk + (size_t)t * HWF);
    const float4* wv4 = reinterpret_cast<const float4*>(Wv + (size_t)t * HWF);
    const float4* m4  = reinterpret_cast<const float4*>(mrow);
    float kt = 0.f, vt = 0.f;
    #pragma unroll 8
    for (int i = 0; i < HWF / 4; ++i) {
        const float4 m = m4[i];
        const float4 a = wk4[i];
        const float4 b = wv4[i];
        kt += m.x * a.x + m.y * a.y + m.z * a.z + m.w * a.w;
        vt += m.x * b.x + m.y * b.y + m.z * b.z + m.w * b.w;
    }

    // mean(k) over 256 features
    red[t] = kt; __syncthreads();
    for (int s = 128; s > 0; s >>= 1) {
        if (t < s) red[t] += red[t + s];
        __syncthreads();
    }
    const float kmean = red[0] * (1.f / HWF);
    __syncthreads();

    const float kcv = kt - kmean;
    red[t] = kcv * kcv; __syncthreads();
    for (int s = 128; s > 0; s >>= 1) {
        if (t < s) red[t] += red[t + s];
        __syncthreads();
    }
    const float kvar = red[0] * (1.f / (HWF - 1));  // unbiased (ddof=1)

    kc[(size_t)j * HWF + t]   = kcv;   // centered k (makes q-centering unnecessary)
    vout[(size_t)j * HWF + t] = vt;
    if (t == 0) { km[j] = kmean; kv[j] = kvar; }
}

// ---------------------------------------------------------------------------
// Kernel 2: fused q-projection + SSIM + online softmax + att@V.
// One block per 64 token rows, 256 threads.
// Thread decomposition: rg = t>>4 (4 rows rg*4..+3), cg = t&15.
//   cov phase: 4x4 acc over [64r x 64j] tile (cg indexes j-groups)
//   attv phase: 4 rows x 16 cols O in registers (cg indexes col-group)
// Trick: cov = sum_k q[r][k]*kc[j][k] with kc centered => q need not be centered
// (sum_k kc = 0 exactly up to fp32 rounding), so Q stays raw; qm only enters ssim.
// ---------------------------------------------------------------------------
__global__ __launch_bounds__(256, 1) void fused_attn(
    const float* __restrict__ x, const float* __restrict__ Wq,
    const float* __restrict__ kcg, const float* __restrict__ vg,
    const float* __restrict__ kmg, const float* __restrict__ kvg,
    float* __restrict__ out)
{
    __shared__ __align__(16) float Qt[HWF * QT_S];  // 69632 B  q transposed [k][r]
    __shared__ __align__(16) float KV[TJ * V_S];    // 66560 B  x-stage / K-tile / V-tile
    __shared__ __align__(16) float Pt[TM * P_S];    // 16640 B  ssim -> p tile
    __shared__ float qmS[TM], qvS[TM], mS[TM], lS[TM], aS[TM], kmS[TJ], kvS[TJ];

    const int t  = threadIdx.x;
    const int n0 = blockIdx.x * TM;
    const int rg = t >> 4;   // 0..15
    const int cg = t & 15;   // 0..15

    // ---- stage x tile (64x256) into KV region, coalesced ----
    #pragma unroll 16
    for (int i = 0; i < TM; ++i)
        KV[i * HWF + t] = x[(size_t)(n0 + i) * HWF + t];
    __syncthreads();

    // ---- q[r][t] for all 64 rows: thread t owns output feature t ----
    float qreg[TM];
    #pragma unroll
    for (int r = 0; r < TM; ++r) qreg[r] = 0.f;
    {
        const float4* wq4 = reinterpret_cast<const float4*>(Wq + (size_t)t * HWF);
        for (int c8 = 0; c8 < HWF / 4; c8 += 8) {
            float4 w[8];
            #pragma unroll
            for (int i = 0; i < 8; ++i) w[i] = wq4[c8 + i];
            #pragma unroll 8
            for (int r = 0; r < TM; ++r) {
                const float4* xr = reinterpret_cast<const float4*>(KV + r * HWF) + c8;
                float a0 = 0.f;
                #pragma unroll
                for (int i = 0; i < 8; ++i) {
                    const float4 xv = xr[i];   // LDS broadcast read
                    a0 += xv.x * w[i].x + xv.y * w[i].y + xv.z * w[i].z + xv.w * w[i].w;
                }
                qreg[r] += a0;
            }
        }
    }
    // write q transposed: Qt[k=t][r], float4 over r
    #pragma unroll
    for (int r4 = 0; r4 < TM / 4; ++r4) {
        *reinterpret_cast<float4*>(Qt + t * QT_S + 4 * r4) =
            make_float4(qreg[4*r4], qreg[4*r4+1], qreg[4*r4+2], qreg[4*r4+3]);
    }
    __syncthreads();

    // ---- per-row stats qm, qv (unbiased) ----
    if (t < TM) {
        float s = 0.f, ss = 0.f;
        for (int k = 0; k < HWF; ++k) {
            const float q = Qt[k * QT_S + t];
            s += q; ss += q * q;
        }
        const float qm = s * (1.f / HWF);
        qmS[t] = qm;
        qvS[t] = (ss - s * s * (1.f / HWF)) * (1.f / (HWF - 1));
        mS[t] = -INFINITY;
        lS[t] = 0.f;
    }
    __syncthreads();

    // ---- online-softmax accumulator ----
    float O[4][16];
    #pragma unroll
    for (int rr = 0; rr < 4; ++rr)
        #pragma unroll
        for (int i = 0; i < 16; ++i) O[rr][i] = 0.f;

    for (int jt = 0; jt < NT; ++jt) {
        const int j0 = jt * TJ;

        // stage K tile (centered k), row-major stride 257; conflict-free writes
        #pragma unroll 16
        for (int i = 0; i < TJ; ++i)
            KV[i * K_S + t] = kcg[(size_t)(j0 + i) * HWF + t];
        if (t < TJ) { kmS[t] = kmg[j0 + t]; kvS[t] = kvg[j0 + t]; }
        __syncthreads();

        // ---- cov GEMM: acc[rr][jj] = sum_k q[r][k] * kc[j][k] ----
        float acc[4][4];
        #pragma unroll
        for (int rr = 0; rr < 4; ++rr)
            #pragma unroll
            for (int jj = 0; jj < 4; ++jj) acc[rr][jj] = 0.f;

        #pragma unroll 4
        for (int k = 0; k < HWF; ++k) {
            const float4 q4 = *reinterpret_cast<const float4*>(Qt + k * QT_S + 4 * rg);
            const float kk0 = KV[(4 * cg + 0) * K_S + k];
            const float kk1 = KV[(4 * cg + 1) * K_S + k];
            const float kk2 = KV[(4 * cg + 2) * K_S + k];
            const float kk3 = KV[(4 * cg + 3) * K_S + k];
            acc[0][0] += q4.x * kk0; acc[0][1] += q4.x * kk1; acc[0][2] += q4.x * kk2; acc[0][3] += q4.x * kk3;
            acc[1][0] += q4.y * kk0; acc[1][1] += q4.y * kk1; acc[1][2] += q4.y * kk2; acc[1][3] += q4.y * kk3;
            acc[2][0] += q4.z * kk0; acc[2][1] += q4.z * kk1; acc[2][2] += q4.z * kk2; acc[2][3] += q4.z * kk3;
            acc[3][0] += q4.w * kk0; acc[3][1] += q4.w * kk1; acc[3][2] += q4.w * kk2; acc[3][3] += q4.w * kk3;
        }

        // ---- ssim -> Pt ----
        #pragma unroll
        for (int rr = 0; rr < 4; ++rr) {
            const float qm  = qmS[4 * rg + rr];
            const float qvv = qvS[4 * rg + rr];
            #pragma unroll
            for (int jj = 0; jj < 4; ++jj) {
                const float km  = kmS[4 * cg + jj];
                const float kvv = kvS[4 * cg + jj];
                const float cov = acc[rr][jj] * (1.f / (HWF - 1));
                const float num = (2.f * qm * km + C1v) * (2.f * cov + C2v);
                const float den = (qm * qm + km * km + C1v) * (qvv + kvv + C2v) + EPSv;
                Pt[(4 * rg + rr) * P_S + 4 * cg + jj] = num / den;
            }
        }
        __syncthreads();

        // ---- online softmax update (one thread per row) ----
        if (t < TM) {
            const float mold = mS[t];
            float mx = mold;
            for (int j = 0; j < TJ; ++j) mx = fmaxf(mx, Pt[t * P_S + j]);
            const float a = __expf(mold - mx);   // first tile: exp(-inf)=0
            float sum = 0.f;
            for (int j = 0; j < TJ; ++j) {
                const float p = __expf(Pt[t * P_S + j] - mx);
                Pt[t * P_S + j] = p;
                sum += p;
            }
            lS[t] = lS[t] * a + sum;
            mS[t] = mx;
            aS[t] = a;
        }
        __syncthreads();

        // ---- rescale O; stage V tile into KV (cov reads of K are done) ----
        {
            const float a0 = aS[4 * rg + 0], a1 = aS[4 * rg + 1];
            const float a2 = aS[4 * rg + 2], a3 = aS[4 * rg + 3];
            #pragma unroll
            for (int i = 0; i < 16; ++i) {
                O[0][i] *= a0; O[1][i] *= a1; O[2][i] *= a2; O[3][i] *= a3;
            }
        }
        #pragma unroll 16
        for (int i = 0; i < TJ; ++i)
            KV[i * V_S + t] = vg[(size_t)(j0 + i) * HWF + t];
        __syncthreads();

        // ---- O += P @ V : thread tile 4 rows x 16 cols ----
        #pragma unroll 2
        for (int j = 0; j < TJ; ++j) {
            const float p0 = Pt[(4 * rg + 0) * P_S + j];
            const float p1 = Pt[(4 * rg + 1) * P_S + j];
            const float p2 = Pt[(4 * rg + 2) * P_S + j];
            const float p3 = Pt[(4 * rg + 3) * P_S + j];
            #pragma unroll
            for (int i4 = 0; i4 < 4; ++i4) {
                const float4 v4 = *reinterpret_cast<const float4*>(KV + j * V_S + 16 * cg + 4 * i4);
                O[0][4*i4+0] += p0 * v4.x; O[0][4*i4+1] += p0 * v4.y; O[0][4*i4+2] += p0 * v4.z; O[0][4*i4+3] += p0 * v4.w;
                O[1][4*i4+0] += p1 * v4.x; O[1][4*i4+1] += p1 * v4.y; O[1][4*i4+2] += p1 * v4.z; O[1][4*i4+3] += p1 * v4.w;
                O[2][4*i4+0] += p2 * v4.x; O[2][4*i4+1] += p2 * v4.y; O[2][4*i4+2] += p2 * v4.z; O[2][4*i4+3] += p2 * v4.w;
                O[3][4*i4+0] += p3 * v4.x; O[3][4*i4+1] += p3 * v4.y; O[3][4*i4+2] += p3 * v4.z; O[3][4*i4+3] += p3 * v4.w;
            }
        }
        __syncthreads();
    }

    // ---- normalize by l and store ----
    #pragma unroll
    for (int rr = 0; rr < 4; ++rr) {
        const float rl = 1.f / lS[4 * rg + rr];
        float* orow = out + (size_t)(n0 + 4 * rg + rr) * HWF + 16 * cg;
        #pragma unroll
        for (int i4 = 0; i4 < 4; ++i4) {
            *reinterpret_cast<float4*>(orow + 4 * i4) =
                make_float4(O[rr][4*i4+0] * rl, O[rr][4*i4+1] * rl,
                            O[rr][4*i4+2] * rl, O[rr][4*i4+3] * rl);
        }
    }
}

extern "C" void kernel_launch(void* const* d_in, const int* in_sizes, int n_in,
                              void* d_out, int out_size, void* d_ws, size_t ws_size,
                              hipStream_t stream) {
    (void)in_sizes; (void)n_in; (void)out_size; (void)ws_size;
    const float* x   = (const float*)d_in[0];   // [65536, 256]
    const float* mem = (const float*)d_in[1];   // [1024, 256]
    const float* Wq  = (const float*)d_in[2];   // [256, 256]
    const float* Wk  = (const float*)d_in[3];
    const float* Wv  = (const float*)d_in[4];
    float* out = (float*)d_out;                 // [65536, 256]

    // workspace: kc[1024*256] | v[1024*256] | km[1024] | kv[1024]  (~2.1 MB)
    float* kc = (float*)d_ws;
    float* v  = kc + (size_t)MEMD * HWF;
    float* km = v  + (size_t)MEMD * HWF;
    float* kv = km + MEMD;

    prep_kv<<<MEMD, 256, 0, stream>>>(mem, Wk, Wv, kc, v, km, kv);
    fused_attn<<<NROWS / TM, 256, 0, stream>>>(x, Wq, kc, v, km, kv, out);
}

// Round 2
// 378.950 us; speedup vs baseline: 5.9721x; 5.9721x over previous
//
#include <hip/hip_runtime.h>
#include <math.h>

typedef __attribute__((ext_vector_type(8))) short bf16x8;   // 8 bf16 = 4 VGPR (guide §3)
typedef __attribute__((ext_vector_type(4))) float f32x4;
typedef __attribute__((ext_vector_type(4))) short short4v;

#define MFMA(a, b, c) __builtin_amdgcn_mfma_f32_16x16x32_bf16((a), (b), (c), 0, 0, 0)

namespace {
constexpr int HWF   = 256;
constexpr int MEMD  = 1024;
constexpr int NROWS = 65536;
constexpr int TM    = 64;          // token rows per block
constexpr int TJ    = 64;          // memory slots per tile
constexpr int NT    = MEMD / TJ;   // 16
constexpr float C1v  = 0.01f;
constexpr float C2v  = 0.03f;
constexpr float EPSv = 1e-8f;
constexpr float RK   = 1.0f / 255.0f;   // 1/(HW-1)
constexpr int PS_STRIDE = 72;      // bf16 units; 144 B rows -> 16B-aligned frag reads
}

__device__ __forceinline__ short f2bf(float f) {           // RNE float->bf16
    union { float f; unsigned u; } v; v.f = f;
    unsigned r = v.u + 0x7fffu + ((v.u >> 16) & 1u);
    return (short)(r >> 16);
}
__device__ __forceinline__ float bf2f(short s) {
    union { unsigned u; float f; } v;
    v.u = ((unsigned)(unsigned short)s) << 16;
    return v.f;
}

// ---------------------------------------------------------------------------
// Wq -> bf16 cast (65536 elements)
// ---------------------------------------------------------------------------
__global__ __launch_bounds__(256) void cast_wq(const float* __restrict__ W,
                                               short* __restrict__ Wb) {
    int i = blockIdx.x * 256 + threadIdx.x;
    Wb[i] = f2bf(W[i]);
}

// ---------------------------------------------------------------------------
// prep: kc = centered(m@Wk^T) as bf16 [j][k]; vt = (m@Wv^T)^T as bf16 [c][j];
// km, kv (unbiased var) fp32. One block per memory slot.
// ---------------------------------------------------------------------------
__global__ __launch_bounds__(256) void prep_kv(
    const float* __restrict__ mem, const float* __restrict__ Wk,
    const float* __restrict__ Wv, short* __restrict__ kc_bf,
    short* __restrict__ vt_bf, float* __restrict__ km, float* __restrict__ kv)
{
    __shared__ __align__(16) float mrow[HWF];
    __shared__ float red[256];
    const int j = blockIdx.x;
    const int t = threadIdx.x;

    mrow[t] = mem[(size_t)j * HWF + t];
    __syncthreads();

    const float4* wk4 = reinterpret_cast<const float4*>(Wk + (size_t)t * HWF);
    const float4* wv4 = reinterpret_cast<const float4*>(Wv + (size_t)t * HWF);
    const float4* m4  = reinterpret_cast<const float4*>(mrow);
    float kt = 0.f, vt = 0.f;
    #pragma unroll 8
    for (int i = 0; i < HWF / 4; ++i) {
        const float4 m = m4[i], a = wk4[i], b = wv4[i];
        kt += m.x * a.x + m.y * a.y + m.z * a.z + m.w * a.w;
        vt += m.x * b.x + m.y * b.y + m.z * b.z + m.w * b.w;
    }

    red[t] = kt; __syncthreads();
    for (int s = 128; s > 0; s >>= 1) { if (t < s) red[t] += red[t + s]; __syncthreads(); }
    const float kmean = red[0] * (1.f / HWF);
    __syncthreads();
    const float kcv = kt - kmean;
    red[t] = kcv * kcv; __syncthreads();
    for (int s = 128; s > 0; s >>= 1) { if (t < s) red[t] += red[t + s]; __syncthreads(); }
    const float kvar = red[0] * (1.f / (HWF - 1));

    kc_bf[(size_t)j * HWF + t]  = f2bf(kcv);
    vt_bf[(size_t)t * MEMD + j] = f2bf(vt);
    if (t == 0) { km[j] = kmean; kv[j] = kvar; }
}

// ---------------------------------------------------------------------------
// Fused: q=x@Wq^T (MFMA) -> stats -> S=q@kc^T (MFMA) -> ssim -> exp -> P@V (MFMA).
// Block = 256 thr (4 waves), 64 token rows; wave w owns rows 16w..16w+16.
// MFMA 16x16x32 layouts (HW-verified): A[m=lane&15][k=(lane>>4)*8+j],
// B[k=(lane>>4)*8+j][n=lane&15], C/D col=lane&15 row=(lane>>4)*4+reg.
// LDS tiles XOR-swizzled in 16B chunks (chunk ^ (row&7)) -> b128 at 8-cyc floor.
// No max-subtraction: |ssim|<=1 by AM-GM, exp never overflows.
// ---------------------------------------------------------------------------
__global__ __launch_bounds__(256, 2) void attn(
    const float* __restrict__ x, const short* __restrict__ wq_bf,
    const short* __restrict__ kc_bf, const short* __restrict__ vt_bf,
    const float* __restrict__ kmg, const float* __restrict__ kvg,
    float* __restrict__ out)
{
    __shared__ __align__(16) char kbuf[64 * 512];           // 32 KB: X-stage, then K tiles
    __shared__ __align__(16) char vbuf[64 * 512];           // 32 KB: q C->A transform, then V tiles
    __shared__ __align__(16) short pS[4 * 16 * PS_STRIDE];  // 9.2 KB: per-wave P C->A transform

    const int t    = threadIdx.x;
    const int wave = t >> 6;
    const int lane = t & 63;
    const int q    = lane >> 4;      // quad 0..3
    const int n    = lane & 15;      // 0..15
    const int n0   = blockIdx.x * TM;
    short* pW = pS + wave * 16 * PS_STRIDE;

    // ---- Phase 0: stage X tile (64x256 fp32 -> bf16, swizzled) into kbuf ----
    {
        const int chunk = lane >> 1, sub = lane & 1;
        #pragma unroll
        for (int i = 0; i < 16; ++i) {
            const int row = i * 4 + wave;
            const float4 xv = *reinterpret_cast<const float4*>(
                x + (size_t)(n0 + row) * HWF + lane * 4);
            short4v b;
            b.x = f2bf(xv.x); b.y = f2bf(xv.y); b.z = f2bf(xv.z); b.w = f2bf(xv.w);
            *reinterpret_cast<short4v*>(
                kbuf + row * 512 + ((chunk ^ (row & 7)) * 16) + sub * 8) = b;
        }
    }
    __syncthreads();

    // ---- Phase 1: q = x @ Wq^T. Wave w: rows 16w..16w+16 x all 256 cols ----
    f32x4 acc16[16];
    #pragma unroll
    for (int i = 0; i < 16; ++i) acc16[i] = (f32x4)(0.f);
    {
        bf16x8 af[8];
        #pragma unroll
        for (int kk = 0; kk < 8; ++kk)
            af[kk] = *reinterpret_cast<const bf16x8*>(
                kbuf + (16 * wave + n) * 512 + (((kk * 4 + q) ^ (n & 7)) * 16));
        #pragma unroll
        for (int nt = 0; nt < 16; ++nt) {
            #pragma unroll
            for (int kk = 0; kk < 8; ++kk) {
                const bf16x8 bfr = *reinterpret_cast<const bf16x8*>(
                    wq_bf + (size_t)(nt * 16 + n) * HWF + kk * 32 + q * 8);
                acc16[nt] = MFMA(af[kk], bfr, acc16[nt]);
            }
        }
    }

    // ---- per-row stats from fp32 q (C-layout rows == later S C-layout rows) ----
    float qm4[4], qv4[4];
    {
        float s[4] = {0,0,0,0}, ss[4] = {0,0,0,0};
        #pragma unroll
        for (int nt = 0; nt < 16; ++nt)
            #pragma unroll
            for (int r = 0; r < 4; ++r) { const float v = acc16[nt][r]; s[r] += v; ss[r] += v * v; }
        #pragma unroll
        for (int r = 0; r < 4; ++r) {
            float a = s[r], b = ss[r];
            #pragma unroll
            for (int m = 1; m < 16; m <<= 1) { a += __shfl_xor(a, m, 16); b += __shfl_xor(b, m, 16); }
            qm4[r] = a * (1.f / HWF);
            qv4[r] = (b - a * a * (1.f / HWF)) * (1.f / (HWF - 1));
        }
    }

    // ---- q C-layout -> bf16 A-frags via swizzled LDS (per-wave private rows) ----
    #pragma unroll
    for (int nt = 0; nt < 16; ++nt) {
        const int chunk = nt * 2 + (n >> 3);
        #pragma unroll
        for (int r = 0; r < 4; ++r) {
            const int row = 16 * wave + q * 4 + r;
            *reinterpret_cast<short*>(
                vbuf + row * 512 + ((chunk ^ (row & 7)) * 16) + (n & 7) * 2) =
                f2bf(acc16[nt][r]);
        }
    }
    bf16x8 aq[8];
    #pragma unroll
    for (int kk = 0; kk < 8; ++kk)
        aq[kk] = *reinterpret_cast<const bf16x8*>(
            vbuf + (16 * wave + n) * 512 + (((kk * 4 + q) ^ (n & 7)) * 16));
    __syncthreads();   // protect vbuf/kbuf before tile staging overwrites

    // ---- main loop: O (acc16 reused) and l accumulate over 16 j-tiles ----
    #pragma unroll
    for (int i = 0; i < 16; ++i) acc16[i] = (f32x4)(0.f);
    float l4[4] = {0, 0, 0, 0};

    for (int jt = 0; jt < NT; ++jt) {
        const int j0 = jt * TJ;

        // stage K tile: 64 rows x 512 B, swizzled; coalesced 16B/lane
        {
            const int jr = t >> 5, ck = t & 31;
            #pragma unroll
            for (int i = 0; i < 8; ++i) {
                const int j = i * 8 + jr;
                const int4 d = *reinterpret_cast<const int4*>(
                    kc_bf + (size_t)(j0 + j) * HWF + ck * 8);
                *reinterpret_cast<int4*>(kbuf + j * 512 + ((ck ^ (j & 7)) * 16)) = d;
            }
        }
        // stage V tile: vt[c][j0..j0+64] -> 256 rows x 128 B, swizzled
        {
            const int cr = t >> 3, ch = t & 7;
            #pragma unroll
            for (int i = 0; i < 8; ++i) {
                const int c = i * 32 + cr;
                const int4 d = *reinterpret_cast<const int4*>(
                    vt_bf + (size_t)c * MEMD + j0 + ch * 8);
                *reinterpret_cast<int4*>(vbuf + c * 128 + ((ch ^ (c & 7)) * 16)) = d;
            }
        }
        __syncthreads();

        // ---- G2: S = q @ kc^T (4 N-tiles), then ssim -> p -> pS ----
        #pragma unroll
        for (int nt = 0; nt < 4; ++nt) {
            f32x4 s = (f32x4)(0.f);
            #pragma unroll
            for (int kk = 0; kk < 8; ++kk) {
                const bf16x8 kb = *reinterpret_cast<const bf16x8*>(
                    kbuf + (nt * 16 + n) * 512 + (((kk * 4 + q) ^ (n & 7)) * 16));
                s = MFMA(aq[kk], kb, s);
            }
            const int j = j0 + nt * 16 + n;
            const float km_ = kmg[j], kv_ = kvg[j];
            #pragma unroll
            for (int r = 0; r < 4; ++r) {
                const float cov = s[r] * RK;
                const float num = (2.f * qm4[r] * km_ + C1v) * (2.f * cov + C2v);
                const float den = (qm4[r] * qm4[r] + km_ * km_ + C1v) *
                                  (qv4[r] + kv_ + C2v) + EPSv;
                const float p = __expf(num / den);
                const short pb = f2bf(p);
                l4[r] += bf2f(pb);                 // l consistent with bf16 P used in O
                pW[(q * 4 + r) * PS_STRIDE + nt * 16 + n] = pb;
            }
        }

        // ---- G3: O += P @ V (A-frags from pS; same-wave lgkmcnt handles dep) ----
        const bf16x8 pa0 = *reinterpret_cast<const bf16x8*>(pW + n * PS_STRIDE + q * 8);
        const bf16x8 pa1 = *reinterpret_cast<const bf16x8*>(pW + n * PS_STRIDE + 32 + q * 8);
        #pragma unroll
        for (int ct = 0; ct < 16; ++ct) {
            const int c = ct * 16 + n;
            const bf16x8 vb0 = *reinterpret_cast<const bf16x8*>(
                vbuf + c * 128 + ((q ^ (c & 7)) * 16));
            const bf16x8 vb1 = *reinterpret_cast<const bf16x8*>(
                vbuf + c * 128 + (((4 + q) ^ (c & 7)) * 16));
            acc16[ct] = MFMA(pa0, vb0, acc16[ct]);
            acc16[ct] = MFMA(pa1, vb1, acc16[ct]);
        }
        __syncthreads();
    }

    // ---- epilogue: reduce l across the 16 lanes of each quad-group, store ----
    #pragma unroll
    for (int r = 0; r < 4; ++r) {
        float a = l4[r];
        #pragma unroll
        for (int m = 1; m < 16; m <<= 1) a += __shfl_xor(a, m, 16);
        l4[r] = 1.f / a;
    }
    #pragma unroll
    for (int ct = 0; ct < 16; ++ct)
        #pragma unroll
        for (int r = 0; r < 4; ++r)
            out[(size_t)(n0 + 16 * wave + q * 4 + r) * HWF + ct * 16 + n] =
                acc16[ct][r] * l4[r];
}

extern "C" void kernel_launch(void* const* d_in, const int* in_sizes, int n_in,
                              void* d_out, int out_size, void* d_ws, size_t ws_size,
                              hipStream_t stream) {
    (void)in_sizes; (void)n_in; (void)out_size; (void)ws_size;
    const float* x   = (const float*)d_in[0];
    const float* mem = (const float*)d_in[1];
    const float* Wq  = (const float*)d_in[2];
    const float* Wk  = (const float*)d_in[3];
    const float* Wv  = (const float*)d_in[4];
    float* out = (float*)d_out;

    // workspace (~1.2 MB): wq_bf | kc_bf | vt_bf | km | kv
    short* wq_bf = (short*)d_ws;                       // 256*256
    short* kc_bf = wq_bf + 256 * 256;                  // 1024*256
    short* vt_bf = kc_bf + (size_t)MEMD * HWF;         // 256*1024
    float* km    = (float*)(vt_bf + (size_t)HWF * MEMD);
    float* kv    = km + MEMD;

    cast_wq<<<256, 256, 0, stream>>>(Wq, wq_bf);
    prep_kv<<<MEMD, 256, 0, stream>>>(mem, Wk, Wv, kc_bf, vt_bf, km, kv);
    attn<<<NROWS / TM, 256, 0, stream>>>(x, wq_bf, kc_bf, vt_bf, km, kv, out);
}

// Round 4
// 287.947 us; speedup vs baseline: 7.8595x; 1.3160x over previous
//
#include <hip/hip_runtime.h>
#include <math.h>

typedef __attribute__((ext_vector_type(8)))  short bf16x8;   // 8 bf16 = 4 VGPR
typedef __attribute__((ext_vector_type(16))) float f32x16;   // 32x32 MFMA acc

#define MFMA32(a, b, c) __builtin_amdgcn_mfma_f32_32x32x16_bf16((a), (b), (c), 0, 0, 0)

namespace {
constexpr int HWF   = 256;
constexpr int MEMD  = 1024;
constexpr int NROWS = 65536;
constexpr int TM    = 128;          // token rows per block
constexpr int TJ    = 64;           // memory slots per tile
constexpr int NT    = MEMD / TJ;    // 16
constexpr int THREADS = 512;        // 8 waves: 4 row-groups x 2 col-splits
constexpr float C1v  = 0.01f;
constexpr float C2v  = 0.03f;
constexpr float EPSv = 1e-8f;
constexpr float RK   = 1.0f / 255.0f;

// LDS map (bytes). q-image (64KB) aliases K0+K1; barriers separate uses.
constexpr int KB0 = 0;                    // 32 KB K tile buf 0
constexpr int KB1 = 32768;                // 32 KB K tile buf 1
constexpr int VB0 = 65536;                // 32 KB V tile buf 0
constexpr int VB1 = 98304;                // 32 KB V tile buf 1
constexpr int PB  = 131072;               // P: 128 rows x 144 B
constexpr int PSTRIDE = 144;              // 16B-aligned
constexpr int QSTAT = PB + TM * PSTRIDE;  // float2[128] (qm,qv); reused as 1/l at end
constexpr int QPART = QSTAT + 1024;       // float2[128][2] partials; reused for l partials
constexpr int SMEM_SZ = QPART + 2048;     // 152576 B < 160 KiB
}

__device__ __forceinline__ short f2bf(float f) {            // RNE float->bf16
    union { float f; unsigned u; } v; v.f = f;
    unsigned r = v.u + 0x7fffu + ((v.u >> 16) & 1u);
    return (short)(r >> 16);
}
__device__ __forceinline__ float bf2f(short s) {
    union { unsigned u; float f; } v;
    v.u = ((unsigned)(unsigned short)s) << 16;
    return v.f;
}

// async global->LDS DMA: 32 KB tile, wave w copies bytes [w*4096, w*4096+4096)
__device__ __forceinline__ void dma_tile(const short* gbase, char* smem, int ldsbase,
                                         int wave, int lane) {
    const char* g = (const char*)gbase + wave * 4096 + lane * 16;
    char* l = smem + ldsbase + wave * 4096;
    #pragma unroll
    for (int i = 0; i < 4; ++i) {
        __builtin_amdgcn_global_load_lds(
            (const __attribute__((address_space(1))) unsigned int*)(g + i * 1024),
            (__attribute__((address_space(3))) unsigned int*)(l + i * 1024), 16, 0, 0);
    }
}

// ---------------------------------------------------------------------------
// Wq -> bf16 (65536 elems)
// ---------------------------------------------------------------------------
__global__ __launch_bounds__(256) void cast_wq(const float* __restrict__ W,
                                               short* __restrict__ Wb) {
    int i = blockIdx.x * 256 + threadIdx.x;
    Wb[i] = f2bf(W[i]);
}

// ---------------------------------------------------------------------------
// prep: per block 4 memory slots. kc (centered k) -> swizzled K blob,
// v^T -> swizzled V blob ([c][j] tiles), km/kv fp32. W read 4x fewer times
// than R2 (256 blocks x 512 KB = 128 MB through L2/L3).
// Blob tile format == exact LDS image consumed by attn (DMA-able).
// ---------------------------------------------------------------------------
__global__ __launch_bounds__(256) void prep_kv(
    const float* __restrict__ mem, const float* __restrict__ Wk,
    const float* __restrict__ Wv, short* __restrict__ kblob,
    short* __restrict__ vblob, float* __restrict__ km, float* __restrict__ kv)
{
    __shared__ __align__(16) float mrows[4][HWF];
    __shared__ float redS[4][8];
    const int t = threadIdx.x, j0 = blockIdx.x * 4;

    for (int r = 0; r < 4; ++r) mrows[r][t] = mem[(size_t)(j0 + r) * HWF + t];
    __syncthreads();

    const float4* wk4 = reinterpret_cast<const float4*>(Wk + (size_t)t * HWF);
    const float4* wv4 = reinterpret_cast<const float4*>(Wv + (size_t)t * HWF);
    float kt[4] = {0, 0, 0, 0}, vt[4] = {0, 0, 0, 0};
    for (int i = 0; i < 64; ++i) {
        const float4 a = wk4[i], b = wv4[i];
        for (int r = 0; r < 4; ++r) {
            const float4 m = reinterpret_cast<const float4*>(mrows[r])[i];
            kt[r] += m.x * a.x + m.y * a.y + m.z * a.z + m.w * a.w;
            vt[r] += m.x * b.x + m.y * b.y + m.z * b.z + m.w * b.w;
        }
    }

    const int wv_ = t >> 6, ln = t & 63;
    {   // mean partials
        float s[4];
        for (int r = 0; r < 4; ++r) s[r] = kt[r];
        for (int m = 1; m < 64; m <<= 1)
            for (int r = 0; r < 4; ++r) s[r] += __shfl_xor(s[r], m);
        if (ln == 0) {
            for (int r = 0; r < 4; ++r) redS[wv_][r] = s[r];
        }
    }
    __syncthreads();
    float kmv[4], kc4[4];
    for (int r = 0; r < 4; ++r) {
        kmv[r] = (redS[0][r] + redS[1][r] + redS[2][r] + redS[3][r]) * (1.f / HWF);
        kc4[r] = kt[r] - kmv[r];
    }
    {   // var partials
        float s[4];
        for (int r = 0; r < 4; ++r) s[r] = kc4[r] * kc4[r];
        for (int m = 1; m < 64; m <<= 1)
            for (int r = 0; r < 4; ++r) s[r] += __shfl_xor(s[r], m);
        if (ln == 0) {
            for (int r = 0; r < 4; ++r) redS[wv_][4 + r] = s[r];
        }
    }
    __syncthreads();
    float kvv[4];
    for (int r = 0; r < 4; ++r)
        kvv[r] = (redS[0][4+r] + redS[1][4+r] + redS[2][4+r] + redS[3][4+r]) * (1.f / (HWF - 1));

    const int jt = j0 >> 6;
    for (int r = 0; r < 4; ++r) {
        const int ro = (j0 & 63) + r;
        // K blob: [jt][row ro (j)][512B: chunk^(ro&7)][8 bf16]
        kblob[jt * 16384 + ro * 256 + (((t >> 3) ^ (ro & 7)) * 8) + (t & 7)] = f2bf(kc4[r]);
        // V blob: [jt][row c=t (feature)][128B: chunk^(c&7)][8 bf16 over j]
        vblob[jt * 16384 + t * 64 + (((ro >> 3) ^ (t & 7)) * 8) + (ro & 7)] = f2bf(vt[r]);
    }
    if (t < 4) { km[j0 + t] = kmv[t]; kv[j0 + t] = kvv[t]; }
}

// ---------------------------------------------------------------------------
// attn: TM=128 rows/block, 8 waves. Wave (rg=w&3, cs=w>>2): 32 rows (A=q held
// in 64 VGPRs across all 16 j-tiles), col-half cs.
// 32x32x16 MFMA: A[m=lane&31][k=8*(lane>>5)+i], B[k=8*(lane>>5)+i][n=lane&31],
// C/D col=lane&31 row=(reg&3)+8*(reg>>2)+4*(lane>>5)  (C/D HW-verified m74/m101).
// K/V staged by global_load_lds DMA from pre-swizzled blobs, double-buffered;
// DMA issued AFTER each barrier so the vmcnt(0) drain hits completed loads.
// ---------------------------------------------------------------------------
__global__ __launch_bounds__(THREADS, 2) void attn(
    const float* __restrict__ x, const short* __restrict__ wq_bf,
    const short* __restrict__ kblob, const short* __restrict__ vblob,
    const float* __restrict__ kmg, const float* __restrict__ kvg,
    float* __restrict__ out)
{
    __shared__ __align__(16) char smem[SMEM_SZ];
    const int t = threadIdx.x, wave = t >> 6, lane = t & 63;
    const int lo = lane & 31, hi = lane >> 5;
    const int rg = wave & 3, cs = wave >> 2;
    const int n0 = blockIdx.x * TM;
    const int arow = 32 * rg + lo;          // this lane's A row (token row in block)

    // ---- phase 1a: X A-frags straight from global (fp32 -> bf16) ----
    bf16x8 qA[16];
    {
        const float* xr = x + (size_t)(n0 + arow) * HWF;
        #pragma unroll
        for (int s = 0; s < 16; ++s) {
            const float4 a = *reinterpret_cast<const float4*>(xr + 16 * s + 8 * hi);
            const float4 b = *reinterpret_cast<const float4*>(xr + 16 * s + 8 * hi + 4);
            bf16x8 f;
            f[0]=f2bf(a.x); f[1]=f2bf(a.y); f[2]=f2bf(a.z); f[3]=f2bf(a.w);
            f[4]=f2bf(b.x); f[5]=f2bf(b.y); f[6]=f2bf(b.z); f[7]=f2bf(b.w);
            qA[s] = f;
        }
    }

    // ---- phase 1b: q = x @ Wq^T (B-frags straight from global bf16 Wq) ----
    f32x16 O4[4];
    #pragma unroll
    for (int i = 0; i < 4; ++i) O4[i] = (f32x16)(0.f);
    #pragma unroll
    for (int nt = 0; nt < 4; ++nt) {
        #pragma unroll
        for (int s = 0; s < 16; ++s) {
            const bf16x8 wb = *reinterpret_cast<const bf16x8*>(
                wq_bf + (size_t)(128 * cs + 32 * nt + lo) * HWF + 16 * s + 8 * hi);
            O4[nt] = MFMA32(qA[s], wb, O4[nt]);
        }
    }

    // ---- stats partials + q -> swizzled q-image (aliases K bufs) ----
    #pragma unroll
    for (int i = 0; i < 16; ++i) {
        float sv  = O4[0][i] + O4[1][i] + O4[2][i] + O4[3][i];
        float ssv = O4[0][i]*O4[0][i] + O4[1][i]*O4[1][i]
                  + O4[2][i]*O4[2][i] + O4[3][i]*O4[3][i];
        #pragma unroll
        for (int m = 1; m < 32; m <<= 1) { sv += __shfl_xor(sv, m); ssv += __shfl_xor(ssv, m); }
        if (lo == 0) {
            const int row = 32 * rg + (i & 3) + 8 * (i >> 2) + 4 * hi;
            *reinterpret_cast<float2*>(smem + QPART + (row * 2 + cs) * 8) =
                make_float2(sv, ssv);
        }
    }
    #pragma unroll
    for (int nt = 0; nt < 4; ++nt) {
        #pragma unroll
        for (int i = 0; i < 16; ++i) {
            const int row = 32 * rg + (i & 3) + 8 * (i >> 2) + 4 * hi;
            const int k = 128 * cs + 32 * nt + lo;
            *reinterpret_cast<short*>(
                smem + row * 512 + (((k >> 3) ^ (row & 7)) * 16) + (k & 7) * 2) =
                f2bf(O4[nt][i]);
        }
    }
    __syncthreads();

    if (t < TM) {
        const float2 p0 = *reinterpret_cast<float2*>(smem + QPART + (t * 2 + 0) * 8);
        const float2 p1 = *reinterpret_cast<float2*>(smem + QPART + (t * 2 + 1) * 8);
        const float s = p0.x + p1.x, ss = p0.y + p1.y;
        const float qm = s * (1.f / HWF);
        const float qv = (ss - s * s * (1.f / HWF)) * (1.f / (HWF - 1));
        *reinterpret_cast<float2*>(smem + QSTAT + t * 8) = make_float2(qm, qv);
    }
    __syncthreads();

    // ---- q A-frags (resident for all 16 tiles) + per-row stats to regs ----
    #pragma unroll
    for (int s = 0; s < 16; ++s)
        qA[s] = *reinterpret_cast<const bf16x8*>(
            smem + arow * 512 + (((2 * s + hi) ^ (arow & 7)) * 16));
    float qm16[16], qv16[16];
    #pragma unroll
    for (int i = 0; i < 16; ++i) {
        const int row = 32 * rg + (i & 3) + 8 * (i >> 2) + 4 * hi;
        const float2 st = *reinterpret_cast<const float2*>(smem + QSTAT + row * 8);
        qm16[i] = st.x; qv16[i] = st.y;
    }
    __syncthreads();   // q-image region free -> becomes K DMA bufs

    // ---- prologue DMA tile 0 ----
    dma_tile(kblob, smem, KB0, wave, lane);
    dma_tile(vblob, smem, VB0, wave, lane);

    float l16[16];
    #pragma unroll
    for (int i = 0; i < 16; ++i) l16[i] = 0.f;
    #pragma unroll
    for (int i = 0; i < 4; ++i) O4[i] = (f32x16)(0.f);

    const int brow = 32 * cs + lo;          // K-tile row (j in tile) this lane reads

    for (int jt = 0; jt < NT; ++jt) {
        const int cur = jt & 1;
        const int kb = cur ? KB1 : KB0, vb = cur ? VB1 : VB0;
        const int kbn = cur ? KB0 : KB1, vbn = cur ? VB0 : VB1;
        __syncthreads();                    // drains DMA(jt); prev PV done
        if (jt + 1 < NT) {                  // prefetch AFTER barrier -> stays in flight
            dma_tile(kblob + (size_t)(jt + 1) * 16384, smem, kbn, wave, lane);
            dma_tile(vblob + (size_t)(jt + 1) * 16384, smem, vbn, wave, lane);
        }

        // ---- S = q @ kc^T : 16 MFMA, 16 b128 reads ----
        f32x16 sacc = (f32x16)(0.f);
        #pragma unroll
        for (int s = 0; s < 16; ++s) {
            const bf16x8 kfr = *reinterpret_cast<const bf16x8*>(
                smem + kb + brow * 512 + (((2 * s + hi) ^ (brow & 7)) * 16));
            sacc = MFMA32(qA[s], kfr, sacc);
        }

        // ---- ssim -> p (no max-sub: |ssim|<=1 by AM-GM) -> P LDS ----
        const int j = 64 * jt + 32 * cs + lo;
        const float km_ = kmg[j], kv_ = kvg[j];
        const float A1 = 2.f * km_, kk1 = km_ * km_ + C1v, kk2 = kv_ + C2v;
        #pragma unroll
        for (int i = 0; i < 16; ++i) {
            const float cov2 = __builtin_fmaf(sacc[i], 2.f * RK, C2v);
            const float num  = __builtin_fmaf(A1, qm16[i], C1v) * cov2;
            const float den  = __builtin_fmaf(
                __builtin_fmaf(qm16[i], qm16[i], kk1), (qv16[i] + kk2), EPSv);
            const float p = __expf(__fdividef(num, den));
            const short pb = f2bf(p);
            l16[i] += bf2f(pb);             // l consistent with bf16 P fed to MFMA
            const int row = 32 * rg + (i & 3) + 8 * (i >> 2) + 4 * hi;
            *reinterpret_cast<short*>(smem + PB + row * PSTRIDE + (32 * cs + lo) * 2) = pb;
        }
        __syncthreads();                    // P complete (cs-pair shares rows)

        // ---- O += P @ V : 4 A-reads + 16 B-reads, 16 MFMA ----
        bf16x8 pa[4];
        #pragma unroll
        for (int s = 0; s < 4; ++s)
            pa[s] = *reinterpret_cast<const bf16x8*>(
                smem + PB + arow * PSTRIDE + 32 * s + 16 * hi);
        #pragma unroll
        for (int ct = 0; ct < 4; ++ct) {
            const int c = 128 * cs + 32 * ct + lo;
            #pragma unroll
            for (int s = 0; s < 4; ++s) {
                const bf16x8 vfr = *reinterpret_cast<const bf16x8*>(
                    smem + vb + c * 128 + (((2 * s + hi) ^ (c & 7)) * 16));
                O4[ct] = MFMA32(pa[s], vfr, O4[ct]);
            }
        }
    }

    // ---- l: reduce over 32 lanes, cross cs-pair via LDS ----
    #pragma unroll
    for (int i = 0; i < 16; ++i) {
        float sv = l16[i];
        #pragma unroll
        for (int m = 1; m < 32; m <<= 1) sv += __shfl_xor(sv, m);
        if (lo == 0) {
            const int row = 32 * rg + (i & 3) + 8 * (i >> 2) + 4 * hi;
            *reinterpret_cast<float*>(smem + QPART + (row * 2 + cs) * 4) = sv;
        }
    }
    __syncthreads();
    if (t < TM) {
        const float a = *reinterpret_cast<float*>(smem + QPART + (t * 2 + 0) * 4);
        const float b = *reinterpret_cast<float*>(smem + QPART + (t * 2 + 1) * 4);
        *reinterpret_cast<float*>(smem + QSTAT + t * 4) = 1.f / (a + b);
    }
    __syncthreads();

    #pragma unroll
    for (int ct = 0; ct < 4; ++ct) {
        #pragma unroll
        for (int i = 0; i < 16; ++i) {
            const int row = 32 * rg + (i & 3) + 8 * (i >> 2) + 4 * hi;
            const float rl = *reinterpret_cast<const float*>(smem + QSTAT + row * 4);
            out[(size_t)(n0 + row) * HWF + 128 * cs + 32 * ct + lo] = O4[ct][i] * rl;
        }
    }
}

extern "C" void kernel_launch(void* const* d_in, const int* in_sizes, int n_in,
                              void* d_out, int out_size, void* d_ws, size_t ws_size,
                              hipStream_t stream) {
    (void)in_sizes; (void)n_in; (void)out_size; (void)ws_size;
    const float* x   = (const float*)d_in[0];
    const float* mem = (const float*)d_in[1];
    const float* Wq  = (const float*)d_in[2];
    const float* Wk  = (const float*)d_in[3];
    const float* Wv  = (const float*)d_in[4];
    float* out = (float*)d_out;

    // workspace (~1.2 MB): wq_bf | kblob | vblob | km | kv
    short* wq_bf = (short*)d_ws;                        // 65536
    short* kblob = wq_bf + 65536;                       // 262144 (16 tiles x 16384)
    short* vblob = kblob + (size_t)MEMD * HWF;          // 262144
    float* km    = (float*)(vblob + (size_t)MEMD * HWF);
    float* kv    = km + MEMD;

    cast_wq<<<256, 256, 0, stream>>>(Wq, wq_bf);
    prep_kv<<<MEMD / 4, 256, 0, stream>>>(mem, Wk, Wv, kblob, vblob, km, kv);
    attn<<<NROWS / TM, THREADS, 0, stream>>>(x, wq_bf, kblob, vblob, km, kv, out);
}